// Round 1
// baseline (139.324 us; speedup 1.0000x reference)
//
#include <hip/hip_runtime.h>

// LinearAttention on MI355X (gfx950).
// b=16, DIM=256, HIDDEN=128 (4 heads x 32), n=4096 pixels, SCALE=1/sqrt(32).
// Strategy: fp16 MFMA (16x16x32) for both GEMMs; softmax without max-subtract
// (logits bounded by ~20); k-weights shifted by exp(k-10) to fit fp16;
// W_out folded with context into per-batch M (256x128) so the tail is one GEMM
// with a fused bias+rmsnorm epilogue.
// Workspace layout (needs ~85.4 MB):
//   W16   fp16[384*256]          @ 0
//   x_t   fp16[16][4096][256]    @ 196608        (xn = x*rsqrt(sumsq)*g*16, transposed)
//   qhat  fp16[16][4096][128]    @ 33751040      (softmaxed q, transposed)
//   kv    fp16[16][256][4096]    @ 50528256      (rows 0-127 = k, 128-255 = v)
//   ctx   f32 [16][4][32][32]    @ 84082688      (atomic-accumulated)
//   sumexp f32[16][4][32]        @ 84344832
//   M     fp16[16][256][128]     @ 84353024

typedef _Float16 half8 __attribute__((ext_vector_type(8)));
typedef _Float16 half4 __attribute__((ext_vector_type(4)));
typedef float f32x4 __attribute__((ext_vector_type(4)));

#define SCALE_F 0.17677669529663687f

// ---------------- k0: W_qkv f32 -> fp16 ----------------
__global__ __launch_bounds__(256) void k0_cvt(const float* __restrict__ W,
                                              _Float16* __restrict__ W16) {
  int idx = blockIdx.x * 256 + threadIdx.x;      // 24576 float4 groups
  f32x4 v = *(const f32x4*)(W + (size_t)idx * 4);
  half4 h = {(_Float16)v[0], (_Float16)v[1], (_Float16)v[2], (_Float16)v[3]};
  *(half4*)(W16 + (size_t)idx * 4) = h;
}

// ---------------- k1: rmsnorm-fold + transpose x -> x_t fp16 [b][p][c] ----
__global__ __launch_bounds__(256) void k1_prep(const float* __restrict__ x,
                                               const float* __restrict__ g_norm,
                                               _Float16* __restrict__ x_t) {
  const int b = blockIdx.y;
  const int p0 = blockIdx.x * 64;
  const int t = threadIdx.x;
  __shared__ _Float16 tile[256][68];   // [ch][px], 136B rows (8B aligned, odd 16B count)
  __shared__ float g16s[256];
  __shared__ float psum[64][4];
  __shared__ float sinv[64];
  g16s[t] = g_norm[t] * 16.0f;
  const float* xb = x + (size_t)b * 256 * 4096;
  #pragma unroll
  for (int it = 0; it < 16; ++it) {
    int c = it * 16 + (t >> 4);
    int px = (t & 15) * 4;
    f32x4 v = *(const f32x4*)(xb + (size_t)c * 4096 + p0 + px);
    half4 h = {(_Float16)v[0], (_Float16)v[1], (_Float16)v[2], (_Float16)v[3]};
    *(half4*)&tile[c][px] = h;
  }
  __syncthreads();
  {
    int px = t & 63, q = t >> 6;
    float s = 0.f;
    #pragma unroll
    for (int i = 0; i < 64; ++i) {
      float f = (float)tile[q * 64 + i][px];
      s += f * f;
    }
    psum[px][q] = s;
  }
  __syncthreads();
  if (t < 64) {
    float s = psum[t][0] + psum[t][1] + psum[t][2] + psum[t][3];
    sinv[t] = rsqrtf(s + 1e-12f);
  }
  __syncthreads();
  _Float16* xt = x_t + ((size_t)b * 4096 + p0) * 256;
  #pragma unroll
  for (int j = 0; j < 8; ++j) {
    int idx8 = t + 256 * j;            // 2048 chunks of 8 halves
    int px = idx8 >> 5;
    int c8 = (idx8 & 31) * 8;
    float iv = sinv[px];
    half8 h;
    #pragma unroll
    for (int i = 0; i < 8; ++i)
      h[i] = (_Float16)((float)tile[c8 + i][px] * iv * g16s[c8 + i]);
    *(half8*)(xt + (size_t)px * 256 + c8) = h;
  }
}

// ---------------- k2: QKV GEMM (384x256 @ 256x4096 per batch) -------------
// Tiles 128x128, BK=64, 4 waves (2x2), XOR-swizzled LDS.
// mt==0 epilogue: q-softmax (per head, over 32 ch) -> qhat[b][p][128] fp16
// mt==1,2 epilogue: store kv[b][row][p] fp16
__global__ __launch_bounds__(256) void k2_qkv(const _Float16* __restrict__ W16,
                                              const _Float16* __restrict__ x_t,
                                              _Float16* __restrict__ kv,
                                              _Float16* __restrict__ qhat) {
  const int pt = blockIdx.x, mt = blockIdx.y, b = blockIdx.z;
  const int p0 = pt * 128;
  const int t = threadIdx.x;
  const int wid = t >> 6, l = t & 63;
  const int wm = (wid >> 1) * 64, wn = (wid & 1) * 64;
  __shared__ __align__(16) char smem[128 * 132 * 4];  // 67584B: A(16K)+B(16K) / rp
  float* rp = (float*)smem;                            // [128][132]
  const f32x4 fz = {0.f, 0.f, 0.f, 0.f};
  f32x4 acc[4][4];
  #pragma unroll
  for (int i = 0; i < 4; ++i)
    #pragma unroll
    for (int j = 0; j < 4; ++j) acc[i][j] = fz;
  const _Float16* Wbase = W16 + (size_t)mt * 128 * 256;
  const _Float16* Xbase = x_t + ((size_t)b * 4096 + p0) * 256;
  for (int kt = 0; kt < 4; ++kt) {
    #pragma unroll
    for (int i = 0; i < 4; ++i) {
      int ci = t + 256 * i;                  // 1024 chunks (128 rows x 8)
      int r = ci >> 3, c = ci & 7;
      int dst = r * 128 + ((c ^ (r & 7)) << 4);
      *(half8*)(smem + dst)         = *(const half8*)(Wbase + (size_t)r * 256 + kt * 64 + c * 8);
      *(half8*)(smem + 16384 + dst) = *(const half8*)(Xbase + (size_t)r * 256 + kt * 64 + c * 8);
    }
    __syncthreads();
    #pragma unroll
    for (int kk = 0; kk < 2; ++kk) {
      half8 af[4], bf[4];
      int ck = kk * 4 + (l >> 4);
      #pragma unroll
      for (int mf = 0; mf < 4; ++mf) {
        int r = wm + mf * 16 + (l & 15);
        af[mf] = *(const half8*)(smem + r * 128 + ((ck ^ (r & 7)) << 4));
      }
      #pragma unroll
      for (int nf = 0; nf < 4; ++nf) {
        int r = wn + nf * 16 + (l & 15);
        bf[nf] = *(const half8*)(smem + 16384 + r * 128 + ((ck ^ (r & 7)) << 4));
      }
      #pragma unroll
      for (int mf = 0; mf < 4; ++mf)
        #pragma unroll
        for (int nf = 0; nf < 4; ++nf)
          acc[mf][nf] = __builtin_amdgcn_mfma_f32_16x16x32_f16(af[mf], bf[nf], acc[mf][nf], 0, 0, 0);
    }
    __syncthreads();
  }
  // spill acc -> rp[row][px]
  #pragma unroll
  for (int mf = 0; mf < 4; ++mf)
    #pragma unroll
    for (int nf = 0; nf < 4; ++nf)
      #pragma unroll
      for (int rr = 0; rr < 4; ++rr) {
        int r = wm + mf * 16 + (l >> 4) * 4 + rr;
        int px = wn + nf * 16 + (l & 15);
        rp[r * 132 + px] = acc[mf][nf][rr];
      }
  __syncthreads();
  if (mt == 0) {
    // q-softmax over each head's 32 channels per pixel (no max-sub: |logit|<~20)
    int px = t & 127;
    #pragma unroll
    for (int hp = 0; hp < 2; ++hp) {
      int h = (t >> 7) * 2 + hp;
      float w[32];
      float s = 0.f;
      #pragma unroll
      for (int i = 0; i < 32; ++i) { w[i] = __expf(rp[(h * 32 + i) * 132 + px]); s += w[i]; }
      float inv = 1.0f / s;
      #pragma unroll
      for (int i = 0; i < 32; ++i) rp[(h * 32 + i) * 132 + px] = w[i] * inv;
    }
    __syncthreads();
    _Float16* qb = qhat + ((size_t)b * 4096 + p0) * 128;
    #pragma unroll
    for (int j = 0; j < 8; ++j) {
      int idx8 = t + 256 * j;
      int px2 = idx8 >> 4, c8 = (idx8 & 15) * 8;
      half8 h;
      #pragma unroll
      for (int i = 0; i < 8; ++i) h[i] = (_Float16)rp[(c8 + i) * 132 + px2];
      *(half8*)(qb + (size_t)px2 * 128 + c8) = h;
    }
  } else {
    _Float16* kb = kv + ((size_t)(b * 256) + (mt - 1) * 128) * 4096 + p0;
    #pragma unroll
    for (int j = 0; j < 8; ++j) {
      int idx8 = t + 256 * j;
      int r = idx8 >> 4, px8 = (idx8 & 15) * 8;
      half8 h;
      #pragma unroll
      for (int i = 0; i < 8; ++i) h[i] = (_Float16)rp[r * 132 + px8 + i];
      *(half8*)(kb + (size_t)r * 4096 + px8) = h;
    }
  }
}

// ---------------- k4: ctx[d][e] += sum_n exp(k-10)*v, sumexp += sum_n exp(k-10)
// grid 256: (b,h,n-quarter). Each wg streams 32x1024 of k and v, MFMA 32x32.
__global__ __launch_bounds__(256) void k4_ctx(const _Float16* __restrict__ kv,
                                              float* __restrict__ ctx,
                                              float* __restrict__ sumexp) {
  const int g = blockIdx.x;
  const int b = g >> 4, h = (g >> 2) & 3, nq = g & 3;
  const int t = threadIdx.x;
  const int wid = t >> 6, l = t & 63;
  __shared__ _Float16 wT[32 * 128];   // [d][n] swizzled, 256B rows
  __shared__ _Float16 vT[32 * 128];
  __shared__ float sacc[32][8];
  __shared__ float cacc[4][32][33];
  const _Float16* kbase = kv + ((size_t)(b * 256) + h * 32) * 4096 + nq * 1024;
  const _Float16* vbase = kv + ((size_t)(b * 256) + 128 + h * 32) * 4096 + nq * 1024;
  const f32x4 fz = {0.f, 0.f, 0.f, 0.f};
  f32x4 acc00 = fz, acc01 = fz, acc10 = fz, acc11 = fz;
  float sumw = 0.f;
  const int d = t >> 3, c8 = t & 7;
  for (int tile = 0; tile < 8; ++tile) {
    const _Float16* kr = kbase + (size_t)d * 4096 + tile * 128 + c8 * 16;
    const _Float16* vr = vbase + (size_t)d * 4096 + tile * 128 + c8 * 16;
    half8 kv0 = *(const half8*)kr;
    half8 kv1 = *(const half8*)(kr + 8);
    half8 v0 = *(const half8*)vr;
    half8 v1 = *(const half8*)(vr + 8);
    half8 w0, w1;
    #pragma unroll
    for (int i = 0; i < 8; ++i) {
      w0[i] = (_Float16)__expf((float)kv0[i] - 10.f);
      w1[i] = (_Float16)__expf((float)kv1[i] - 10.f);
      sumw += (float)w0[i] + (float)w1[i];
    }
    const int ck0 = c8 * 2, ck1 = c8 * 2 + 1;
    *(half8*)((char*)wT + d * 256 + ((ck0 ^ (d & 15)) << 4)) = w0;
    *(half8*)((char*)wT + d * 256 + ((ck1 ^ (d & 15)) << 4)) = w1;
    *(half8*)((char*)vT + d * 256 + ((ck0 ^ (d & 15)) << 4)) = v0;
    *(half8*)((char*)vT + d * 256 + ((ck1 ^ (d & 15)) << 4)) = v1;
    __syncthreads();
    const int ck = wid * 4 + (l >> 4);   // wave's n-slice
    const int d0 = l & 15, d1 = 16 + (l & 15);
    half8 a0 = *(const half8*)((char*)wT + d0 * 256 + ((ck ^ (d0 & 15)) << 4));
    half8 a1 = *(const half8*)((char*)wT + d1 * 256 + ((ck ^ (d1 & 15)) << 4));
    half8 b0 = *(const half8*)((char*)vT + d0 * 256 + ((ck ^ (d0 & 15)) << 4));
    half8 b1 = *(const half8*)((char*)vT + d1 * 256 + ((ck ^ (d1 & 15)) << 4));
    acc00 = __builtin_amdgcn_mfma_f32_16x16x32_f16(a0, b0, acc00, 0, 0, 0);
    acc01 = __builtin_amdgcn_mfma_f32_16x16x32_f16(a0, b1, acc01, 0, 0, 0);
    acc10 = __builtin_amdgcn_mfma_f32_16x16x32_f16(a1, b0, acc10, 0, 0, 0);
    acc11 = __builtin_amdgcn_mfma_f32_16x16x32_f16(a1, b1, acc11, 0, 0, 0);
    __syncthreads();
  }
  sacc[d][c8] = sumw;
  #pragma unroll
  for (int rr = 0; rr < 4; ++rr) {
    int dd0 = (l >> 4) * 4 + rr;
    int ee0 = l & 15;
    cacc[wid][dd0][ee0]           = acc00[rr];
    cacc[wid][dd0][ee0 + 16]      = acc01[rr];
    cacc[wid][dd0 + 16][ee0]      = acc10[rr];
    cacc[wid][dd0 + 16][ee0 + 16] = acc11[rr];
  }
  __syncthreads();
  if (t < 32) {
    float s = 0.f;
    #pragma unroll
    for (int j = 0; j < 8; ++j) s += sacc[t][j];
    atomicAdd(&sumexp[(b * 4 + h) * 32 + t], s);
  }
  #pragma unroll
  for (int i = 0; i < 4; ++i) {
    int idx = t + 256 * i;
    int dd = idx >> 5, ee = idx & 31;
    float v = cacc[0][dd][ee] + cacc[1][dd][ee] + cacc[2][dd][ee] + cacc[3][dd][ee];
    atomicAdd(&ctx[((size_t)((b * 4 + h) * 32) + dd) * 32 + ee], v);
  }
}

// ---------------- k4b: M[b][c][h*32+d] = SCALE/sumexp * sum_e W_out[c][he]*ctx
__global__ __launch_bounds__(256) void k4b_fold(const float* __restrict__ W_out,
                                                const float* __restrict__ ctx,
                                                const float* __restrict__ sumexp,
                                                _Float16* __restrict__ M) {
  const int b = blockIdx.x, t = threadIdx.x;   // t = output channel c
  __shared__ float sctx[4096];
  __shared__ float sis[128];
  #pragma unroll
  for (int i = 0; i < 16; ++i) sctx[t + 256 * i] = ctx[(size_t)b * 4096 + t + 256 * i];
  if (t < 128) sis[t] = SCALE_F / sumexp[b * 128 + t];
  __syncthreads();
  const float* wrow = W_out + (size_t)t * 128;
  _Float16* mrow = M + ((size_t)(b * 256) + t) * 128;
  #pragma unroll
  for (int h = 0; h < 4; ++h) {
    float w[32];
    #pragma unroll
    for (int e = 0; e < 32; ++e) w[e] = wrow[h * 32 + e];
    #pragma unroll
    for (int d8 = 0; d8 < 4; ++d8) {
      half8 outv;
      #pragma unroll
      for (int dd = 0; dd < 8; ++dd) {
        int dcur = d8 * 8 + dd;
        float s = 0.f;
        #pragma unroll
        for (int e = 0; e < 32; ++e) s += w[e] * sctx[(h * 32 + dcur) * 32 + e];
        outv[dd] = (_Float16)(s * sis[h * 32 + dcur]);
      }
      *(half8*)(mrow + h * 32 + d8 * 8) = outv;
    }
  }
}

// ---------------- k5: out = rmsnorm(M @ qhat + b_out, g_out), f32 ----------
// Tile 256(M-full) x 64, K=128 single-shot, 4 waves stacked on M.
__global__ __launch_bounds__(256) void k5c_out(const _Float16* __restrict__ M,
                                               const _Float16* __restrict__ qhat,
                                               const float* __restrict__ b_out,
                                               const float* __restrict__ g_out,
                                               float* __restrict__ out) {
  const int pt = blockIdx.x, b = blockIdx.y;
  const int p0 = pt * 64;
  const int t = threadIdx.x;
  const int wid = t >> 6, l = t & 63;
  __shared__ __align__(16) char smem[81920];  // A 64K + B 16K | rp 69632 + extras
  float* rp = (float*)smem;                   // [256][68]
  float* bo = (float*)(smem + 69632);
  float* g16o = (float*)(smem + 70656);
  float* psum = (float*)(smem + 71680);       // [64][4]
  float* sinvp = (float*)(smem + 72704);      // [64]
  const _Float16* Mb = M + (size_t)b * 256 * 128;
  const _Float16* Qb = qhat + ((size_t)b * 4096 + p0) * 128;
  #pragma unroll
  for (int i = 0; i < 16; ++i) {              // stage A (M): 4096 chunks
    int ci = t + 256 * i;
    int r = ci >> 4, c = ci & 15;
    *(half8*)(smem + r * 256 + ((c ^ (r & 15)) << 4)) = *(const half8*)(Mb + (size_t)r * 128 + c * 8);
  }
  #pragma unroll
  for (int i = 0; i < 4; ++i) {               // stage B (qhat): 1024 chunks
    int ci = t + 256 * i;
    int r = ci >> 4, c = ci & 15;
    *(half8*)(smem + 65536 + r * 256 + ((c ^ (r & 15)) << 4)) = *(const half8*)(Qb + (size_t)r * 128 + c * 8);
  }
  __syncthreads();
  const f32x4 fz = {0.f, 0.f, 0.f, 0.f};
  f32x4 acc[4][4];
  #pragma unroll
  for (int i = 0; i < 4; ++i)
    #pragma unroll
    for (int j = 0; j < 4; ++j) acc[i][j] = fz;
  #pragma unroll
  for (int kk = 0; kk < 4; ++kk) {
    half8 af[4], bf[4];
    int ck = kk * 4 + (l >> 4);
    #pragma unroll
    for (int mf = 0; mf < 4; ++mf) {
      int r = wid * 64 + mf * 16 + (l & 15);
      af[mf] = *(const half8*)(smem + r * 256 + ((ck ^ (r & 15)) << 4));
    }
    #pragma unroll
    for (int nf = 0; nf < 4; ++nf) {
      int r = nf * 16 + (l & 15);
      bf[nf] = *(const half8*)(smem + 65536 + r * 256 + ((ck ^ (r & 15)) << 4));
    }
    #pragma unroll
    for (int mf = 0; mf < 4; ++mf)
      #pragma unroll
      for (int nf = 0; nf < 4; ++nf)
        acc[mf][nf] = __builtin_amdgcn_mfma_f32_16x16x32_f16(af[mf], bf[nf], acc[mf][nf], 0, 0, 0);
  }
  __syncthreads();   // staging regions dead; rp/extras live from here
  bo[t] = b_out[t];
  g16o[t] = g_out[t] * 16.0f;
  #pragma unroll
  for (int mf = 0; mf < 4; ++mf)
    #pragma unroll
    for (int nf = 0; nf < 4; ++nf)
      #pragma unroll
      for (int rr = 0; rr < 4; ++rr) {
        int r = wid * 64 + mf * 16 + (l >> 4) * 4 + rr;
        int px = nf * 16 + (l & 15);
        rp[r * 68 + px] = acc[mf][nf][rr];
      }
  __syncthreads();
  {
    int px = t & 63, q = t >> 6;
    float s = 0.f;
    #pragma unroll
    for (int i = 0; i < 64; ++i) {
      int r = q * 64 + i;
      float f = rp[r * 68 + px] + bo[r];
      s += f * f;
    }
    psum[px * 4 + q] = s;
  }
  __syncthreads();
  if (t < 64)
    sinvp[t] = rsqrtf(psum[t * 4] + psum[t * 4 + 1] + psum[t * 4 + 2] + psum[t * 4 + 3] + 1e-12f);
  __syncthreads();
  float* ob = out + (size_t)(b * 256) * 4096 + p0;
  #pragma unroll
  for (int i = 0; i < 16; ++i) {
    int idx4 = t + 256 * i;
    int r = idx4 >> 4, px4 = (idx4 & 15) * 4;
    f32x4 v;
    #pragma unroll
    for (int ii = 0; ii < 4; ++ii)
      v[ii] = (rp[r * 68 + px4 + ii] + bo[r]) * sinvp[px4 + ii] * g16o[r];
    *(f32x4*)(ob + (size_t)r * 4096 + px4) = v;
  }
}

extern "C" void kernel_launch(void* const* d_in, const int* in_sizes, int n_in,
                              void* d_out, int out_size, void* d_ws, size_t ws_size,
                              hipStream_t stream) {
  const float* x      = (const float*)d_in[0];
  const float* W_qkv  = (const float*)d_in[1];
  const float* W_out  = (const float*)d_in[2];
  const float* b_out  = (const float*)d_in[3];
  const float* g_norm = (const float*)d_in[4];
  const float* g_out  = (const float*)d_in[5];
  float* out = (float*)d_out;
  char* ws = (char*)d_ws;
  if (ws_size < 85401600) return;  // loud failure if workspace too small

  _Float16* W16  = (_Float16*)(ws);
  _Float16* x_t  = (_Float16*)(ws + 196608);
  _Float16* qhat = (_Float16*)(ws + 33751040);
  _Float16* kv   = (_Float16*)(ws + 50528256);
  float*    ctx  = (float*)(ws + 84082688);
  float*    sume = (float*)(ws + 84344832);
  _Float16* M    = (_Float16*)(ws + 84353024);

  hipMemsetAsync(ctx, 0, 262144 + 8192, stream);  // ctx + sumexp (contiguous)
  k0_cvt<<<96, 256, 0, stream>>>(W_qkv, W16);
  k1_prep<<<dim3(64, 16), 256, 0, stream>>>(x, g_norm, x_t);
  k2_qkv<<<dim3(32, 3, 16), 256, 0, stream>>>(W16, x_t, kv, qhat);
  k4_ctx<<<256, 256, 0, stream>>>(kv, ctx, sume);
  k4b_fold<<<16, 256, 0, stream>>>(W_out, ctx, sume, M);
  k5c_out<<<dim3(64, 16), 256, 0, stream>>>(M, qhat, b_out, g_out, out);
}

// Round 2
// 127.124 us; speedup vs baseline: 1.0960x; 1.0960x over previous
//
#include <hip/hip_runtime.h>

// LinearAttention on MI355X (gfx950) — R2: fused QKV+softmax+ctx kernel.
// b=16, DIM=256, HIDDEN=128 (4 heads x 32), n=4096 px, SCALE=1/sqrt(32).
// k2_fused per (px-tile 128, b): GEMM mt=q,k,v (128x128 tiles, BK=64,
// global_load_lds staging w/ pre-swizzled source); epilogues per 32-row
// quarter: q -> softmax -> qhat; k -> exp(k-10) -> wtile + row sums;
// v -> vbuf -> ctx MFMA + f32 atomics. Grid 512 = 2 blocks/CU, fully resident.
// Workspace:
//   W16   fp16[384*256]        @ 0
//   x_t   fp16[16][4096][256]  @ 196608
//   qhat  fp16[16][4096][128]  @ 33751040
//   ctx   f32 [16][4][32][32]  @ 50528256
//   sume  f32 [16][128]        @ 50790400
//   M     fp16[16][256][128]   @ 50798592   (ends 51847168)

typedef _Float16 half8 __attribute__((ext_vector_type(8)));
typedef _Float16 half4 __attribute__((ext_vector_type(4)));
typedef float f32x4 __attribute__((ext_vector_type(4)));

#define SCALE_F 0.17677669529663687f

#define GLOAD16(g, s) __builtin_amdgcn_global_load_lds( \
    (const __attribute__((address_space(1))) void*)(g), \
    (__attribute__((address_space(3))) void*)(s), 16, 0, 0)

// ---------------- k1: rmsnorm-fold + transpose x -> x_t fp16 [b][p][c];
// blocks with blockIdx.x==64 convert W_qkv f32->fp16 instead. ----
__global__ __launch_bounds__(256) void k1_prep(const float* __restrict__ x,
                                               const float* __restrict__ g_norm,
                                               const float* __restrict__ W_qkv,
                                               _Float16* __restrict__ W16,
                                               _Float16* __restrict__ x_t) {
  const int t = threadIdx.x;
  if (blockIdx.x == 64) {              // W conversion: 16 blocks x 256 thr x 6
    int base = blockIdx.y * 1536 + t;
    #pragma unroll
    for (int i = 0; i < 6; ++i) {
      int idx = base + 256 * i;        // 24576 f32x4 chunks total
      f32x4 v = *(const f32x4*)(W_qkv + (size_t)idx * 4);
      half4 h = {(_Float16)v[0], (_Float16)v[1], (_Float16)v[2], (_Float16)v[3]};
      *(half4*)(W16 + (size_t)idx * 4) = h;
    }
    return;
  }
  const int b = blockIdx.y;
  const int p0 = blockIdx.x * 64;
  __shared__ _Float16 tile[256][68];   // [ch][px]
  __shared__ float g16s[256];
  __shared__ float psum[64][4];
  __shared__ float sinv[64];
  g16s[t] = g_norm[t] * 16.0f;
  const float* xb = x + (size_t)b * 256 * 4096;
  #pragma unroll
  for (int it = 0; it < 16; ++it) {
    int c = it * 16 + (t >> 4);
    int px = (t & 15) * 4;
    f32x4 v = *(const f32x4*)(xb + (size_t)c * 4096 + p0 + px);
    half4 h = {(_Float16)v[0], (_Float16)v[1], (_Float16)v[2], (_Float16)v[3]};
    *(half4*)&tile[c][px] = h;
  }
  __syncthreads();
  {
    int px = t & 63, q = t >> 6;
    float s = 0.f;
    #pragma unroll
    for (int i = 0; i < 64; ++i) {
      float f = (float)tile[q * 64 + i][px];
      s += f * f;
    }
    psum[px][q] = s;
  }
  __syncthreads();
  if (t < 64) {
    float s = psum[t][0] + psum[t][1] + psum[t][2] + psum[t][3];
    sinv[t] = rsqrtf(s + 1e-12f);
  }
  __syncthreads();
  _Float16* xt = x_t + ((size_t)b * 4096 + p0) * 256;
  #pragma unroll
  for (int j = 0; j < 8; ++j) {
    int idx8 = t + 256 * j;
    int px = idx8 >> 5;
    int c8 = (idx8 & 31) * 8;
    float iv = sinv[px];
    half8 h;
    #pragma unroll
    for (int i = 0; i < 8; ++i)
      h[i] = (_Float16)((float)tile[c8 + i][px] * iv * g16s[c8 + i]);
    *(half8*)(xt + (size_t)px * 256 + c8) = h;
  }
}

// ---------------- k2_fused: QKV GEMM + q-softmax + k-exp + ctx ----------
__global__ __launch_bounds__(256, 2) void k2_fused(const _Float16* __restrict__ W16,
                                                   const _Float16* __restrict__ x_t,
                                                   _Float16* __restrict__ qhat,
                                                   float* __restrict__ ctx,
                                                   float* __restrict__ sumexp) {
  const int pt = blockIdx.x, b = blockIdx.y;
  const int p0 = pt * 128;
  const int t = threadIdx.x;
  const int wid = t >> 6, l = t & 63;
  const int wm = (wid >> 1) << 6, wn = (wid & 1) << 6;
  __shared__ __align__(1024) char smem[65536];
  // regions: [0,32K) staging (A 16K | B 16K), overlaid in epilogues by
  //   rp f32[32][132] (16896 B) and vbuf fp16[32][128] @17408 (8 KB);
  // [32K,64K) wtile fp16[128][128] (k-weights, persists mt=1..2).
  float* rp = (float*)smem;
  _Float16* vbuf = (_Float16*)(smem + 17408);
  char* wtile = smem + 32768;
  const _Float16* Xbase = x_t + ((size_t)b * 4096 + p0) * 256;
  _Float16* qb = qhat + ((size_t)b * 4096 + p0) * 128;
  const f32x4 fz = {0.f, 0.f, 0.f, 0.f};
  #pragma unroll
  for (int mt = 0; mt < 3; ++mt) {
    f32x4 acc[4][4];
    #pragma unroll
    for (int i = 0; i < 4; ++i)
      #pragma unroll
      for (int j = 0; j < 4; ++j) acc[i][j] = fz;
    const _Float16* Wmt = W16 + (size_t)(mt * 128) * 256;
    for (int kt = 0; kt < 4; ++kt) {
      #pragma unroll
      for (int i = 0; i < 4; ++i) {
        int q = ((wid * 4 + i) << 6) + l;   // chunk index 0..1023
        int r = q >> 3, s = q & 7;
        int co = kt * 64 + ((s ^ (r & 7)) << 3);   // pre-swizzled source col
        GLOAD16(Wmt + (size_t)r * 256 + co, smem + ((wid * 4 + i) << 10));
        GLOAD16(Xbase + (size_t)r * 256 + co, smem + 16384 + ((wid * 4 + i) << 10));
      }
      __syncthreads();
      #pragma unroll
      for (int kk = 0; kk < 2; ++kk) {
        half8 af[4], bf[4];
        int ck = kk * 4 + (l >> 4);
        #pragma unroll
        for (int mf = 0; mf < 4; ++mf) {
          int r = wm + mf * 16 + (l & 15);
          af[mf] = *(const half8*)(smem + r * 128 + ((ck ^ (r & 7)) << 4));
        }
        #pragma unroll
        for (int nf = 0; nf < 4; ++nf) {
          int r = wn + nf * 16 + (l & 15);
          bf[nf] = *(const half8*)(smem + 16384 + r * 128 + ((ck ^ (r & 7)) << 4));
        }
        #pragma unroll
        for (int mf = 0; mf < 4; ++mf)
          #pragma unroll
          for (int nf = 0; nf < 4; ++nf)
            acc[mf][nf] = __builtin_amdgcn_mfma_f32_16x16x32_f16(af[mf], bf[nf], acc[mf][nf], 0, 0, 0);
      }
      __syncthreads();
    }
    // ---- epilogue in 32-row quarters (quarter qi = head qi for q/k/v) ----
    #pragma unroll
    for (int qi = 0; qi < 4; ++qi) {
      if ((wid >> 1) == (qi >> 1)) {       // owning wave-pair spills quarter
        const int mfb = (qi & 1) << 1;
        #pragma unroll
        for (int mo = 0; mo < 2; ++mo)
          #pragma unroll
          for (int nf = 0; nf < 4; ++nf)
            #pragma unroll
            for (int rr = 0; rr < 4; ++rr)
              rp[(mo * 16 + (l >> 4) * 4 + rr) * 132 + wn + nf * 16 + (l & 15)] =
                  acc[mfb + mo][nf][rr];
      }
      __syncthreads();
      if (mt == 0) {
        // q-softmax over the head's 32 channels (f32 logits, no max-sub)
        int px = t & 127, hf = t >> 7;
        float w[32];
        float ssum = 0.f;
        #pragma unroll
        for (int i = 0; i < 32; ++i) { w[i] = __expf(rp[i * 132 + px]); ssum += w[i]; }
        float inv = 1.0f / ssum;
        if (hf == 0) {
          #pragma unroll
          for (int i = 0; i < 16; ++i) vbuf[i * 128 + px] = (_Float16)(w[i] * inv);
        } else {
          #pragma unroll
          for (int i = 0; i < 16; ++i) vbuf[(16 + i) * 128 + px] = (_Float16)(w[16 + i] * inv);
        }
        __syncthreads();
        #pragma unroll
        for (int i = 0; i < 2; ++i) {      // store qhat[px][qi*32..+32]
          int ci = t + 256 * i;
          int px2 = ci >> 2, c8 = (ci & 3) * 8;
          half8 h;
          #pragma unroll
          for (int j = 0; j < 8; ++j) h[j] = vbuf[(c8 + j) * 128 + px2];
          *(half8*)(qb + (size_t)px2 * 128 + qi * 32 + c8) = h;
        }
        // no barrier: next spill touches rp only; next vbuf write is
        // after the next quarter's barrier.
      } else if (mt == 1) {
        // k: w = exp(logit-10) -> wtile (swizzled); row sums -> atomics
        #pragma unroll
        for (int i = 0; i < 2; ++i) {
          int ci = t + 256 * i;
          int c = ci >> 4, s = ci & 15;
          const float* rr_ = &rp[c * 132 + s * 8];
          float sm = 0.f;
          half8 h;
          #pragma unroll
          for (int j = 0; j < 8; ++j) {
            float e = __expf(rr_[j] - 10.f);
            sm += e;
            h[j] = (_Float16)e;
          }
          int gc = qi * 32 + c;
          *(half8*)(wtile + gc * 256 + ((s ^ (gc & 15)) << 4)) = h;
          sm += __shfl_xor(sm, 1);
          sm += __shfl_xor(sm, 2);
          sm += __shfl_xor(sm, 4);
          sm += __shfl_xor(sm, 8);
          if ((l & 15) == 0) atomicAdd(&sumexp[b * 128 + gc], sm);
        }
        __syncthreads();                   // rp reuse next quarter
      } else {
        // v: -> vbuf (swizzled); then wave qi: ctx += w_h v_h^T (K=128 px)
        #pragma unroll
        for (int i = 0; i < 2; ++i) {
          int ci = t + 256 * i;
          int c = ci >> 4, s = ci & 15;
          const float* rr_ = &rp[c * 132 + s * 8];
          half8 h;
          #pragma unroll
          for (int j = 0; j < 8; ++j) h[j] = (_Float16)rr_[j];
          *(half8*)((char*)vbuf + c * 256 + ((s ^ (c & 15)) << 4)) = h;
        }
        __syncthreads();
        if (wid == qi) {
          f32x4 ca[2][2] = {{fz, fz}, {fz, fz}};
          #pragma unroll
          for (int kk = 0; kk < 4; ++kk) {
            half8 a2[2], b2[2];
            int sl = kk * 4 + (l >> 4);
            #pragma unroll
            for (int ti = 0; ti < 2; ++ti) {
              int gc = qi * 32 + ti * 16 + (l & 15);
              a2[ti] = *(const half8*)(wtile + gc * 256 + ((sl ^ (gc & 15)) << 4));
              int lc = ti * 16 + (l & 15);
              b2[ti] = *(const half8*)((char*)vbuf + lc * 256 + ((sl ^ (lc & 15)) << 4));
            }
            #pragma unroll
            for (int ti = 0; ti < 2; ++ti)
              #pragma unroll
              for (int tj = 0; tj < 2; ++tj)
                ca[ti][tj] = __builtin_amdgcn_mfma_f32_16x16x32_f16(a2[ti], b2[tj], ca[ti][tj], 0, 0, 0);
          }
          float* cb = ctx + (size_t)(b * 4 + qi) * 1024;
          #pragma unroll
          for (int ti = 0; ti < 2; ++ti)
            #pragma unroll
            for (int tj = 0; tj < 2; ++tj)
              #pragma unroll
              for (int rr = 0; rr < 4; ++rr)
                atomicAdd(&cb[(ti * 16 + (l >> 4) * 4 + rr) * 32 + tj * 16 + (l & 15)],
                          ca[ti][tj][rr]);
        }
        // mfma-wave reaches next quarter's barrier after finishing ->
        // vbuf overwrite is ordered. Last quarter: kernel end.
      }
    }
    if (mt < 2) __syncthreads();           // protect rp/vbuf region before next staging
  }
}

// ---------------- k4b: M[b][c][hd] = SCALE/sume[hd] * sum_e W_out[c][he]*ctx
__global__ __launch_bounds__(256) void k4b_fold(const float* __restrict__ W_out,
                                                const float* __restrict__ ctx,
                                                const float* __restrict__ sumexp,
                                                _Float16* __restrict__ M) {
  const int b = blockIdx.x, t = threadIdx.x;
  __shared__ float sctx[4096];
  __shared__ float sis[128];
  #pragma unroll
  for (int i = 0; i < 16; ++i) sctx[t + 256 * i] = ctx[(size_t)b * 4096 + t + 256 * i];
  if (t < 128) sis[t] = SCALE_F / sumexp[b * 128 + t];
  __syncthreads();
  const float* wrow = W_out + (size_t)t * 128;
  _Float16* mrow = M + ((size_t)(b * 256) + t) * 128;
  #pragma unroll
  for (int h = 0; h < 4; ++h) {
    float w[32];
    #pragma unroll
    for (int e = 0; e < 32; ++e) w[e] = wrow[h * 32 + e];
    #pragma unroll
    for (int d8 = 0; d8 < 4; ++d8) {
      half8 outv;
      #pragma unroll
      for (int dd = 0; dd < 8; ++dd) {
        int dcur = d8 * 8 + dd;
        float s = 0.f;
        #pragma unroll
        for (int e = 0; e < 32; ++e) s += w[e] * sctx[(h * 32 + dcur) * 32 + e];
        outv[dd] = (_Float16)(s * sis[h * 32 + dcur]);
      }
      *(half8*)(mrow + h * 32 + d8 * 8) = outv;
    }
  }
}

// ---------------- k5: out = rmsnorm(M @ qhat + b_out, g_out), f32 ----------
__global__ __launch_bounds__(256) void k5c_out(const _Float16* __restrict__ M,
                                               const _Float16* __restrict__ qhat,
                                               const float* __restrict__ b_out,
                                               const float* __restrict__ g_out,
                                               float* __restrict__ out) {
  const int pt = blockIdx.x, b = blockIdx.y;
  const int p0 = pt * 64;
  const int t = threadIdx.x;
  const int wid = t >> 6, l = t & 63;
  __shared__ __align__(16) char smem[81920];
  float* rp = (float*)smem;                   // [256][68]
  float* bo = (float*)(smem + 69632);
  float* g16o = (float*)(smem + 70656);
  float* psum = (float*)(smem + 71680);
  float* sinvp = (float*)(smem + 72704);
  const _Float16* Mb = M + (size_t)b * 256 * 128;
  const _Float16* Qb = qhat + ((size_t)b * 4096 + p0) * 128;
  #pragma unroll
  for (int i = 0; i < 16; ++i) {
    int ci = t + 256 * i;
    int r = ci >> 4, c = ci & 15;
    *(half8*)(smem + r * 256 + ((c ^ (r & 15)) << 4)) = *(const half8*)(Mb + (size_t)r * 128 + c * 8);
  }
  #pragma unroll
  for (int i = 0; i < 4; ++i) {
    int ci = t + 256 * i;
    int r = ci >> 4, c = ci & 15;
    *(half8*)(smem + 65536 + r * 256 + ((c ^ (r & 15)) << 4)) = *(const half8*)(Qb + (size_t)r * 128 + c * 8);
  }
  __syncthreads();
  const f32x4 fz = {0.f, 0.f, 0.f, 0.f};
  f32x4 acc[4][4];
  #pragma unroll
  for (int i = 0; i < 4; ++i)
    #pragma unroll
    for (int j = 0; j < 4; ++j) acc[i][j] = fz;
  #pragma unroll
  for (int kk = 0; kk < 4; ++kk) {
    half8 af[4], bf[4];
    int ck = kk * 4 + (l >> 4);
    #pragma unroll
    for (int mf = 0; mf < 4; ++mf) {
      int r = wid * 64 + mf * 16 + (l & 15);
      af[mf] = *(const half8*)(smem + r * 256 + ((ck ^ (r & 15)) << 4));
    }
    #pragma unroll
    for (int nf = 0; nf < 4; ++nf) {
      int r = nf * 16 + (l & 15);
      bf[nf] = *(const half8*)(smem + 65536 + r * 256 + ((ck ^ (r & 15)) << 4));
    }
    #pragma unroll
    for (int mf = 0; mf < 4; ++mf)
      #pragma unroll
      for (int nf = 0; nf < 4; ++nf)
        acc[mf][nf] = __builtin_amdgcn_mfma_f32_16x16x32_f16(af[mf], bf[nf], acc[mf][nf], 0, 0, 0);
  }
  __syncthreads();
  bo[t] = b_out[t];
  g16o[t] = g_out[t] * 16.0f;
  #pragma unroll
  for (int mf = 0; mf < 4; ++mf)
    #pragma unroll
    for (int nf = 0; nf < 4; ++nf)
      #pragma unroll
      for (int rr = 0; rr < 4; ++rr) {
        int r = wid * 64 + mf * 16 + (l >> 4) * 4 + rr;
        int px = nf * 16 + (l & 15);
        rp[r * 68 + px] = acc[mf][nf][rr];
      }
  __syncthreads();
  {
    int px = t & 63, q = t >> 6;
    float s = 0.f;
    #pragma unroll
    for (int i = 0; i < 64; ++i) {
      int r = q * 64 + i;
      float f = rp[r * 68 + px] + bo[r];
      s += f * f;
    }
    psum[px * 4 + q] = s;
  }
  __syncthreads();
  if (t < 64)
    sinvp[t] = rsqrtf(psum[t * 4] + psum[t * 4 + 1] + psum[t * 4 + 2] + psum[t * 4 + 3] + 1e-12f);
  __syncthreads();
  float* ob = out + (size_t)(b * 256) * 4096 + p0;
  #pragma unroll
  for (int i = 0; i < 16; ++i) {
    int idx4 = t + 256 * i;
    int r = idx4 >> 4, px4 = (idx4 & 15) * 4;
    f32x4 v;
    #pragma unroll
    for (int ii = 0; ii < 4; ++ii)
      v[ii] = (rp[r * 68 + px4 + ii] + bo[r]) * sinvp[px4 + ii] * g16o[r];
    *(f32x4*)(ob + (size_t)r * 4096 + px4) = v;
  }
}

extern "C" void kernel_launch(void* const* d_in, const int* in_sizes, int n_in,
                              void* d_out, int out_size, void* d_ws, size_t ws_size,
                              hipStream_t stream) {
  const float* x      = (const float*)d_in[0];
  const float* W_qkv  = (const float*)d_in[1];
  const float* W_out  = (const float*)d_in[2];
  const float* b_out  = (const float*)d_in[3];
  const float* g_norm = (const float*)d_in[4];
  const float* g_out  = (const float*)d_in[5];
  float* out = (float*)d_out;
  char* ws = (char*)d_ws;
  if (ws_size < 51847168) return;

  _Float16* W16  = (_Float16*)(ws);
  _Float16* x_t  = (_Float16*)(ws + 196608);
  _Float16* qhat = (_Float16*)(ws + 33751040);
  float*    ctx  = (float*)(ws + 50528256);
  float*    sume = (float*)(ws + 50790400);
  _Float16* M    = (_Float16*)(ws + 50798592);

  hipMemsetAsync(ctx, 0, 262144 + 8192, stream);
  k1_prep<<<dim3(65, 16), 256, 0, stream>>>(x, g_norm, W_qkv, W16, x_t);
  k2_fused<<<dim3(32, 16), 256, 0, stream>>>(W16, x_t, qhat, ctx, sume);
  k4b_fold<<<16, 256, 0, stream>>>(W_out, ctx, sume, M);
  k5c_out<<<dim3(64, 16), 256, 0, stream>>>(M, qhat, b_out, g_out, out);
}

// Round 3
// 88.097 us; speedup vs baseline: 1.5815x; 1.4430x over previous
//
#include <hip/hip_runtime.h>

// LinearAttention on MI355X (gfx950) — R3.
// R3 changes vs R2: k4b rewritten as MFMA (was 40us latency-bound scalar-LDS
// loop); memset dispatch folded into k1 (zero ctx/sume); W_out converted to
// fp16 in k1's W-conversion blocks.
// Workspace:
//   W16   fp16[384*256]        @ 0
//   x_t   fp16[16][4096][256]  @ 196608
//   qhat  fp16[16][4096][128]  @ 33751040
//   ctx   f32 [16][4][32][32]  @ 50528256
//   sume  f32 [16][128]        @ 50790400
//   M     fp16[16][256][128]   @ 50798592
//   Wo16  fp16[256*128]        @ 51847168  (ends 51912704)

typedef _Float16 half8 __attribute__((ext_vector_type(8)));
typedef _Float16 half4 __attribute__((ext_vector_type(4)));
typedef float f32x4 __attribute__((ext_vector_type(4)));

#define SCALE_F 0.17677669529663687f

#define GLOAD16(g, s) __builtin_amdgcn_global_load_lds( \
    (const __attribute__((address_space(1))) void*)(g), \
    (__attribute__((address_space(3))) void*)(s), 16, 0, 0)

// ---------------- k1: rmsnorm-fold + transpose x -> x_t fp16 [b][p][c];
// x==64: convert W_qkv + W_out to fp16; x==65: zero ctx+sume. ----
__global__ __launch_bounds__(256) void k1_prep(const float* __restrict__ x,
                                               const float* __restrict__ g_norm,
                                               const float* __restrict__ W_qkv,
                                               const float* __restrict__ W_out,
                                               _Float16* __restrict__ W16,
                                               _Float16* __restrict__ Wo16,
                                               float* __restrict__ zbase,
                                               _Float16* __restrict__ x_t) {
  const int t = threadIdx.x;
  if (blockIdx.x == 64) {              // W conversion: 16 blocks x 256 thr x 8
    #pragma unroll
    for (int i = 0; i < 8; ++i) {
      int idx = blockIdx.y * 2048 + i * 256 + t;   // 32768 f32x4 chunks
      f32x4 v;
      if (idx < 24576) v = *(const f32x4*)(W_qkv + (size_t)idx * 4);
      else             v = *(const f32x4*)(W_out + (size_t)(idx - 24576) * 4);
      half4 h = {(_Float16)v[0], (_Float16)v[1], (_Float16)v[2], (_Float16)v[3]};
      if (idx < 24576) *(half4*)(W16 + (size_t)idx * 4) = h;
      else             *(half4*)(Wo16 + (size_t)(idx - 24576) * 4) = h;
    }
    return;
  }
  if (blockIdx.x == 65) {              // zero ctx (256K) + sume (8K): 270336 B
    const f32x4 fz = {0.f, 0.f, 0.f, 0.f};
    float* zb = zbase + blockIdx.y * 4224;         // 16896 B per y-block
    for (int off = t * 4; off < 4224; off += 1024)
      *(f32x4*)(zb + off) = fz;
    return;
  }
  const int b = blockIdx.y;
  const int p0 = blockIdx.x * 64;
  __shared__ _Float16 tile[256][68];   // [ch][px]
  __shared__ float g16s[256];
  __shared__ float psum[64][4];
  __shared__ float sinv[64];
  g16s[t] = g_norm[t] * 16.0f;
  const float* xb = x + (size_t)b * 256 * 4096;
  #pragma unroll
  for (int it = 0; it < 16; ++it) {
    int c = it * 16 + (t >> 4);
    int px = (t & 15) * 4;
    f32x4 v = *(const f32x4*)(xb + (size_t)c * 4096 + p0 + px);
    half4 h = {(_Float16)v[0], (_Float16)v[1], (_Float16)v[2], (_Float16)v[3]};
    *(half4*)&tile[c][px] = h;
  }
  __syncthreads();
  {
    int px = t & 63, q = t >> 6;
    float s = 0.f;
    #pragma unroll
    for (int i = 0; i < 64; ++i) {
      float f = (float)tile[q * 64 + i][px];
      s += f * f;
    }
    psum[px][q] = s;
  }
  __syncthreads();
  if (t < 64) {
    float s = psum[t][0] + psum[t][1] + psum[t][2] + psum[t][3];
    sinv[t] = rsqrtf(s + 1e-12f);
  }
  __syncthreads();
  _Float16* xt = x_t + ((size_t)b * 4096 + p0) * 256;
  #pragma unroll
  for (int j = 0; j < 8; ++j) {
    int idx8 = t + 256 * j;
    int px = idx8 >> 5;
    int c8 = (idx8 & 31) * 8;
    float iv = sinv[px];
    half8 h;
    #pragma unroll
    for (int i = 0; i < 8; ++i)
      h[i] = (_Float16)((float)tile[c8 + i][px] * iv * g16s[c8 + i]);
    *(half8*)(xt + (size_t)px * 256 + c8) = h;
  }
}

// ---------------- k2_fused: QKV GEMM + q-softmax + k-exp + ctx ----------
__global__ __launch_bounds__(256, 2) void k2_fused(const _Float16* __restrict__ W16,
                                                   const _Float16* __restrict__ x_t,
                                                   _Float16* __restrict__ qhat,
                                                   float* __restrict__ ctx,
                                                   float* __restrict__ sumexp) {
  const int pt = blockIdx.x, b = blockIdx.y;
  const int p0 = pt * 128;
  const int t = threadIdx.x;
  const int wid = t >> 6, l = t & 63;
  const int wm = (wid >> 1) << 6, wn = (wid & 1) << 6;
  __shared__ __align__(1024) char smem[65536];
  float* rp = (float*)smem;
  _Float16* vbuf = (_Float16*)(smem + 17408);
  char* wtile = smem + 32768;
  const _Float16* Xbase = x_t + ((size_t)b * 4096 + p0) * 256;
  _Float16* qb = qhat + ((size_t)b * 4096 + p0) * 128;
  const f32x4 fz = {0.f, 0.f, 0.f, 0.f};
  #pragma unroll
  for (int mt = 0; mt < 3; ++mt) {
    f32x4 acc[4][4];
    #pragma unroll
    for (int i = 0; i < 4; ++i)
      #pragma unroll
      for (int j = 0; j < 4; ++j) acc[i][j] = fz;
    const _Float16* Wmt = W16 + (size_t)(mt * 128) * 256;
    for (int kt = 0; kt < 4; ++kt) {
      #pragma unroll
      for (int i = 0; i < 4; ++i) {
        int q = ((wid * 4 + i) << 6) + l;
        int r = q >> 3, s = q & 7;
        int co = kt * 64 + ((s ^ (r & 7)) << 3);
        GLOAD16(Wmt + (size_t)r * 256 + co, smem + ((wid * 4 + i) << 10));
        GLOAD16(Xbase + (size_t)r * 256 + co, smem + 16384 + ((wid * 4 + i) << 10));
      }
      __syncthreads();
      #pragma unroll
      for (int kk = 0; kk < 2; ++kk) {
        half8 af[4], bf[4];
        int ck = kk * 4 + (l >> 4);
        #pragma unroll
        for (int mf = 0; mf < 4; ++mf) {
          int r = wm + mf * 16 + (l & 15);
          af[mf] = *(const half8*)(smem + r * 128 + ((ck ^ (r & 7)) << 4));
        }
        #pragma unroll
        for (int nf = 0; nf < 4; ++nf) {
          int r = wn + nf * 16 + (l & 15);
          bf[nf] = *(const half8*)(smem + 16384 + r * 128 + ((ck ^ (r & 7)) << 4));
        }
        #pragma unroll
        for (int mf = 0; mf < 4; ++mf)
          #pragma unroll
          for (int nf = 0; nf < 4; ++nf)
            acc[mf][nf] = __builtin_amdgcn_mfma_f32_16x16x32_f16(af[mf], bf[nf], acc[mf][nf], 0, 0, 0);
      }
      __syncthreads();
    }
    #pragma unroll
    for (int qi = 0; qi < 4; ++qi) {
      if ((wid >> 1) == (qi >> 1)) {
        const int mfb = (qi & 1) << 1;
        #pragma unroll
        for (int mo = 0; mo < 2; ++mo)
          #pragma unroll
          for (int nf = 0; nf < 4; ++nf)
            #pragma unroll
            for (int rr = 0; rr < 4; ++rr)
              rp[(mo * 16 + (l >> 4) * 4 + rr) * 132 + wn + nf * 16 + (l & 15)] =
                  acc[mfb + mo][nf][rr];
      }
      __syncthreads();
      if (mt == 0) {
        int px = t & 127, hf = t >> 7;
        float w[32];
        float ssum = 0.f;
        #pragma unroll
        for (int i = 0; i < 32; ++i) { w[i] = __expf(rp[i * 132 + px]); ssum += w[i]; }
        float inv = 1.0f / ssum;
        if (hf == 0) {
          #pragma unroll
          for (int i = 0; i < 16; ++i) vbuf[i * 128 + px] = (_Float16)(w[i] * inv);
        } else {
          #pragma unroll
          for (int i = 0; i < 16; ++i) vbuf[(16 + i) * 128 + px] = (_Float16)(w[16 + i] * inv);
        }
        __syncthreads();
        #pragma unroll
        for (int i = 0; i < 2; ++i) {
          int ci = t + 256 * i;
          int px2 = ci >> 2, c8 = (ci & 3) * 8;
          half8 h;
          #pragma unroll
          for (int j = 0; j < 8; ++j) h[j] = vbuf[(c8 + j) * 128 + px2];
          *(half8*)(qb + (size_t)px2 * 128 + qi * 32 + c8) = h;
        }
      } else if (mt == 1) {
        #pragma unroll
        for (int i = 0; i < 2; ++i) {
          int ci = t + 256 * i;
          int c = ci >> 4, s = ci & 15;
          const float* rr_ = &rp[c * 132 + s * 8];
          float sm = 0.f;
          half8 h;
          #pragma unroll
          for (int j = 0; j < 8; ++j) {
            float e = __expf(rr_[j] - 10.f);
            sm += e;
            h[j] = (_Float16)e;
          }
          int gc = qi * 32 + c;
          *(half8*)(wtile + gc * 256 + ((s ^ (gc & 15)) << 4)) = h;
          sm += __shfl_xor(sm, 1);
          sm += __shfl_xor(sm, 2);
          sm += __shfl_xor(sm, 4);
          sm += __shfl_xor(sm, 8);
          if ((l & 15) == 0) atomicAdd(&sumexp[b * 128 + gc], sm);
        }
        __syncthreads();
      } else {
        #pragma unroll
        for (int i = 0; i < 2; ++i) {
          int ci = t + 256 * i;
          int c = ci >> 4, s = ci & 15;
          const float* rr_ = &rp[c * 132 + s * 8];
          half8 h;
          #pragma unroll
          for (int j = 0; j < 8; ++j) h[j] = (_Float16)rr_[j];
          *(half8*)((char*)vbuf + c * 256 + ((s ^ (c & 15)) << 4)) = h;
        }
        __syncthreads();
        if (wid == qi) {
          f32x4 ca[2][2] = {{fz, fz}, {fz, fz}};
          #pragma unroll
          for (int kk = 0; kk < 4; ++kk) {
            half8 a2[2], b2[2];
            int sl = kk * 4 + (l >> 4);
            #pragma unroll
            for (int ti = 0; ti < 2; ++ti) {
              int gc = qi * 32 + ti * 16 + (l & 15);
              a2[ti] = *(const half8*)(wtile + gc * 256 + ((sl ^ (gc & 15)) << 4));
              int lc = ti * 16 + (l & 15);
              b2[ti] = *(const half8*)((char*)vbuf + lc * 256 + ((sl ^ (lc & 15)) << 4));
            }
            #pragma unroll
            for (int ti = 0; ti < 2; ++ti)
              #pragma unroll
              for (int tj = 0; tj < 2; ++tj)
                ca[ti][tj] = __builtin_amdgcn_mfma_f32_16x16x32_f16(a2[ti], b2[tj], ca[ti][tj], 0, 0, 0);
          }
          float* cb = ctx + (size_t)(b * 4 + qi) * 1024;
          #pragma unroll
          for (int ti = 0; ti < 2; ++ti)
            #pragma unroll
            for (int tj = 0; tj < 2; ++tj)
              #pragma unroll
              for (int rr = 0; rr < 4; ++rr)
                atomicAdd(&cb[(ti * 16 + (l >> 4) * 4 + rr) * 32 + tj * 16 + (l & 15)],
                          ca[ti][tj][rr]);
        }
      }
    }
    if (mt < 2) __syncthreads();
  }
}

// ---------------- k4b: M_h = W_out16[:,h*32..] @ (ctx^T * SCALE/sume), MFMA.
// grid (4,16): x = row-quarter, y = b. Wave = head.
__global__ __launch_bounds__(256) void k4b_fold(const _Float16* __restrict__ Wo16,
                                                const float* __restrict__ ctx,
                                                const float* __restrict__ sumexp,
                                                _Float16* __restrict__ M) {
  const int mq = blockIdx.x, b = blockIdx.y;
  const int t = threadIdx.x;
  const int h = t >> 6, l = t & 63;
  const int m0 = mq * 64;
  const float* cb = ctx + (size_t)(b * 4 + h) * 1024;
  const float* sb = sumexp + b * 128 + h * 32;
  half8 bf[2];
  #pragma unroll
  for (int n0 = 0; n0 < 2; ++n0) {
    int d = n0 * 16 + (l & 15);
    float s = SCALE_F / sb[d];
    const float* ce = cb + d * 32 + (l >> 4) * 8;
    half8 hb;
    #pragma unroll
    for (int j = 0; j < 8; ++j) hb[j] = (_Float16)(ce[j] * s);
    bf[n0] = hb;
  }
  const f32x4 fz = {0.f, 0.f, 0.f, 0.f};
  _Float16* Mb = M + (size_t)(b * 256) * 128;
  #pragma unroll
  for (int mf = 0; mf < 4; ++mf) {
    int row = m0 + mf * 16 + (l & 15);
    half8 af = *(const half8*)(Wo16 + (size_t)row * 128 + h * 32 + (l >> 4) * 8);
    #pragma unroll
    for (int n0 = 0; n0 < 2; ++n0) {
      f32x4 c = __builtin_amdgcn_mfma_f32_16x16x32_f16(af, bf[n0], fz, 0, 0, 0);
      #pragma unroll
      for (int rr = 0; rr < 4; ++rr) {
        int r = m0 + mf * 16 + (l >> 4) * 4 + rr;
        Mb[(size_t)r * 128 + h * 32 + n0 * 16 + (l & 15)] = (_Float16)c[rr];
      }
    }
  }
}

// ---------------- k5: out = rmsnorm(M @ qhat + b_out, g_out), f32 ----------
__global__ __launch_bounds__(256) void k5c_out(const _Float16* __restrict__ M,
                                               const _Float16* __restrict__ qhat,
                                               const float* __restrict__ b_out,
                                               const float* __restrict__ g_out,
                                               float* __restrict__ out) {
  const int pt = blockIdx.x, b = blockIdx.y;
  const int p0 = pt * 64;
  const int t = threadIdx.x;
  const int wid = t >> 6, l = t & 63;
  __shared__ __align__(16) char smem[81920];
  float* rp = (float*)smem;                   // [256][68]
  float* bo = (float*)(smem + 69632);
  float* g16o = (float*)(smem + 70656);
  float* psum = (float*)(smem + 71680);
  float* sinvp = (float*)(smem + 72704);
  const _Float16* Mb = M + (size_t)b * 256 * 128;
  const _Float16* Qb = qhat + ((size_t)b * 4096 + p0) * 128;
  #pragma unroll
  for (int i = 0; i < 16; ++i) {
    int ci = t + 256 * i;
    int r = ci >> 4, c = ci & 15;
    *(half8*)(smem + r * 256 + ((c ^ (r & 15)) << 4)) = *(const half8*)(Mb + (size_t)r * 128 + c * 8);
  }
  #pragma unroll
  for (int i = 0; i < 4; ++i) {
    int ci = t + 256 * i;
    int r = ci >> 4, c = ci & 15;
    *(half8*)(smem + 65536 + r * 256 + ((c ^ (r & 15)) << 4)) = *(const half8*)(Qb + (size_t)r * 128 + c * 8);
  }
  __syncthreads();
  const f32x4 fz = {0.f, 0.f, 0.f, 0.f};
  f32x4 acc[4][4];
  #pragma unroll
  for (int i = 0; i < 4; ++i)
    #pragma unroll
    for (int j = 0; j < 4; ++j) acc[i][j] = fz;
  #pragma unroll
  for (int kk = 0; kk < 4; ++kk) {
    half8 af[4], bf[4];
    int ck = kk * 4 + (l >> 4);
    #pragma unroll
    for (int mf = 0; mf < 4; ++mf) {
      int r = wid * 64 + mf * 16 + (l & 15);
      af[mf] = *(const half8*)(smem + r * 256 + ((ck ^ (r & 15)) << 4));
    }
    #pragma unroll
    for (int nf = 0; nf < 4; ++nf) {
      int r = nf * 16 + (l & 15);
      bf[nf] = *(const half8*)(smem + 65536 + r * 256 + ((ck ^ (r & 15)) << 4));
    }
    #pragma unroll
    for (int mf = 0; mf < 4; ++mf)
      #pragma unroll
      for (int nf = 0; nf < 4; ++nf)
        acc[mf][nf] = __builtin_amdgcn_mfma_f32_16x16x32_f16(af[mf], bf[nf], acc[mf][nf], 0, 0, 0);
  }
  __syncthreads();
  bo[t] = b_out[t];
  g16o[t] = g_out[t] * 16.0f;
  #pragma unroll
  for (int mf = 0; mf < 4; ++mf)
    #pragma unroll
    for (int nf = 0; nf < 4; ++nf)
      #pragma unroll
      for (int rr = 0; rr < 4; ++rr) {
        int r = wid * 64 + mf * 16 + (l >> 4) * 4 + rr;
        int px = nf * 16 + (l & 15);
        rp[r * 68 + px] = acc[mf][nf][rr];
      }
  __syncthreads();
  {
    int px = t & 63, q = t >> 6;
    float s = 0.f;
    #pragma unroll
    for (int i = 0; i < 64; ++i) {
      int r = q * 64 + i;
      float f = rp[r * 68 + px] + bo[r];
      s += f * f;
    }
    psum[px * 4 + q] = s;
  }
  __syncthreads();
  if (t < 64)
    sinvp[t] = rsqrtf(psum[t * 4] + psum[t * 4 + 1] + psum[t * 4 + 2] + psum[t * 4 + 3] + 1e-12f);
  __syncthreads();
  float* ob = out + (size_t)(b * 256) * 4096 + p0;
  #pragma unroll
  for (int i = 0; i < 16; ++i) {
    int idx4 = t + 256 * i;
    int r = idx4 >> 4, px4 = (idx4 & 15) * 4;
    f32x4 v;
    #pragma unroll
    for (int ii = 0; ii < 4; ++ii)
      v[ii] = (rp[r * 68 + px4 + ii] + bo[r]) * sinvp[px4 + ii] * g16o[r];
    *(f32x4*)(ob + (size_t)r * 4096 + px4) = v;
  }
}

extern "C" void kernel_launch(void* const* d_in, const int* in_sizes, int n_in,
                              void* d_out, int out_size, void* d_ws, size_t ws_size,
                              hipStream_t stream) {
  const float* x      = (const float*)d_in[0];
  const float* W_qkv  = (const float*)d_in[1];
  const float* W_out  = (const float*)d_in[2];
  const float* b_out  = (const float*)d_in[3];
  const float* g_norm = (const float*)d_in[4];
  const float* g_out  = (const float*)d_in[5];
  float* out = (float*)d_out;
  char* ws = (char*)d_ws;
  if (ws_size < 51912704) return;

  _Float16* W16  = (_Float16*)(ws);
  _Float16* x_t  = (_Float16*)(ws + 196608);
  _Float16* qhat = (_Float16*)(ws + 33751040);
  float*    ctx  = (float*)(ws + 50528256);
  float*    sume = (float*)(ws + 50790400);
  _Float16* M    = (_Float16*)(ws + 50798592);
  _Float16* Wo16 = (_Float16*)(ws + 51847168);

  k1_prep<<<dim3(66, 16), 256, 0, stream>>>(x, g_norm, W_qkv, W_out, W16, Wo16, ctx, x_t);
  k2_fused<<<dim3(32, 16), 256, 0, stream>>>(W16, x_t, qhat, ctx, sume);
  k4b_fold<<<dim3(4, 16), 256, 0, stream>>>(Wo16, ctx, sume, M);
  k5c_out<<<dim3(64, 16), 256, 0, stream>>>(M, qhat, b_out, g_out, out);
}